// Round 3
// baseline (598.389 us; speedup 1.0000x reference)
//
#include <hip/hip_runtime.h>
#include <math.h>

#define NC 19683
#define KN 26
#define DD 128
#define HGN 64
#define CB 24          // cells per block
#define LDSB 136
#define DTC 0.1f

using bf8v = __attribute__((ext_vector_type(8))) short;
using f4v  = __attribute__((ext_vector_type(4))) float;

static __device__ __forceinline__ unsigned short f2bf(float x) {
    union { float f; unsigned u; } v; v.f = x;
    unsigned r = v.u + 0x7fffu + ((v.u >> 16) & 1u);
    return (unsigned short)(r >> 16);
}
static __device__ __forceinline__ unsigned pk2(float a, float b) {
    return ((unsigned)f2bf(a)) | (((unsigned)f2bf(b)) << 16);
}

// ---------------- prep: transpose 4x [256,128] f32 weights -> [128][256] bf16; Wg1 -> [64][128] bf16 ----
__global__ __launch_bounds__(256) void k_prep(const float* __restrict__ Wl,
    const float* __restrict__ Wm, const float* __restrict__ Wu,
    const float* __restrict__ Wc, const float* __restrict__ Wg1,
    unsigned short* __restrict__ WT, unsigned short* __restrict__ WgT)
{
    int idx = blockIdx.x * 256 + threadIdx.x;   // 544*256 = 139264 exact
    if (idx < 131072) {
        int m = idx >> 15;
        int r = idx & 32767;
        int j = r >> 8;     // 0..127 output col
        int i = r & 255;    // 0..255 k
        const float* src = (m == 0) ? Wl : (m == 1) ? Wm : (m == 2) ? Wu : Wc;
        WT[idx] = f2bf(src[i * DD + j]);
    } else {
        int idx2 = idx - 131072;        // 0..8191
        int col = idx2 >> 7;            // 0..63
        int k = idx2 & 127;             // 0..127
        WgT[idx2] = f2bf(Wg1[k * HGN + col]);
    }
}

// ---------------- kMega: whole op, 24 cells/block, per-cell-independent ----------------
// U arena rows: 0..127 Al(4 slices x 32), 128..151 Xc, 152..175 agL, 176..199 agM,
//               200..223 agD, 224..231 pad (absorbs mt=1 OOB reads of agD rows 24..31)
#define ALr(c,k) (U + ((c) * 32 + (k)) * LDSB)
#define XCr(r)   (U + (128 + (r)) * LDSB)
#define AGLr(r)  (U + (152 + (r)) * LDSB)
#define AGMr(r)  (U + (176 + (r)) * LDSB)
#define AGDr(r)  (U + (200 + (r)) * LDSB)

__global__ __launch_bounds__(256, 2) void kMega(
    const float* __restrict__ cur, const float* __restrict__ nbr,
    const int* __restrict__ conn, const unsigned short* __restrict__ WT,
    const unsigned short* __restrict__ WgT, const float* __restrict__ b_msg,
    const float* __restrict__ b_local, const float* __restrict__ b_upd,
    const float* __restrict__ b_cnf, const float* __restrict__ bg1,
    const float* __restrict__ Wg2, const float* __restrict__ bg2,
    float* __restrict__ out)
{
    __shared__ __align__(16) unsigned short U[232 * LDSB];   // 63,104 B
    __shared__ __align__(16) float uP[CB * DD];              // hrelu early / P later (12,288 B)
    __shared__ float glds[32][4];
    __shared__ float bl[DD], bu[DD], bc[DD];
    __shared__ float Wg2s[HGN * 3];
    __shared__ float bg2s[4];

    int t = threadIdx.x;
    int n0 = blockIdx.x * CB;
    int w = t >> 6, lane = t & 63;
    int lm = lane & 15, lq = lane >> 4;
    int mt = w & 1, colh = w >> 1;

    // ---- prologue: stage Xc (cur -> bf16), biases, gate-head weights ----
    for (int p = 0; p < 6; ++p) {
        int idx = p * 256 + t;              // 1536 = 24 rows * 64 float2
        int r = idx >> 6, c2 = (idx & 63) * 2;
        float2 v = {0.f, 0.f};
        if (n0 + r < NC) v = *(const float2*)&cur[(size_t)(n0 + r) * DD + c2];
        *(unsigned*)&XCr(r)[c2] = pk2(v.x, v.y);
    }
    if (t < 128) { bl[t] = b_local[t]; bu[t] = b_upd[t]; bc[t] = b_cnf[t]; }
    for (int i = t; i < HGN * 3; i += 256) Wg2s[i] = Wg2[i];
    if (t < 3) bg2s[t] = bg2[t];
    __syncthreads();

    // ---- gates MFMA: wave w -> cols w*16..w*16+15; hrelu into uP (stride 68) ----
    {
        int col0 = w * 16;
        float bg = bg1[col0 + lm];
        for (int mt2 = 0; mt2 < 2; ++mt2) {
            f4v acc = {0.f, 0.f, 0.f, 0.f};
            #pragma unroll
            for (int s = 0; s < 4; ++s) {
                bf8v a = *(const bf8v*)&XCr(mt2 * 16 + lm)[s * 32 + lq * 8];
                bf8v b = *(const bf8v*)&WgT[(col0 + lm) * 128 + s * 32 + lq * 8];
                acc = __builtin_amdgcn_mfma_f32_16x16x32_bf16(a, b, acc, 0, 0, 0);
            }
            for (int r = 0; r < 4; ++r) {
                int row = mt2 * 16 + lq * 4 + r;
                if (row < CB) uP[row * 68 + col0 + lm] = fmaxf(acc[r] + bg, 0.f);
            }
        }
    }
    __syncthreads();

    // ---- gate logits (72 threads) ----
    if (t < CB * 3) {
        int r = t / 3, e = t - r * 3;
        float s = bg2s[e];
        for (int g = 0; g < HGN; ++g) s += uP[r * 68 + g] * Wg2s[g * 3 + e];
        glds[r][e] = s;
    }
    __syncthreads();            // hrelu consumed; uP becomes P

    // ---- P-pass: P[24][128] = Xc @ Wm1 + b_msg ; wave w -> cols w*32..w*32+31 ----
    {
        const unsigned short* Wm1 = WT + 32768;
        for (int nt = 0; nt < 2; ++nt) {
            int col0 = w * 32 + nt * 16;
            float bm = b_msg[col0 + lm];
            const unsigned short* bb = &Wm1[(col0 + lm) * 256 + lq * 8];
            for (int mt2 = 0; mt2 < 2; ++mt2) {
                f4v acc = {0.f, 0.f, 0.f, 0.f};
                #pragma unroll
                for (int s = 0; s < 4; ++s) {
                    bf8v a = *(const bf8v*)&XCr(mt2 * 16 + lm)[s * 32 + lq * 8];
                    bf8v b = *(const bf8v*)&bb[s * 32];
                    acc = __builtin_amdgcn_mfma_f32_16x16x32_bf16(a, b, acc, 0, 0, 0);
                }
                for (int r = 0; r < 4; ++r) {
                    int row = mt2 * 16 + lq * 4 + r;
                    if (row < CB) uP[row * DD + col0 + lm] = acc[r] + bm;
                }
            }
        }
    }
    // softmax (t<24) — glds rows all written before the previous barrier
    if (t < CB) {
        float l0 = glds[t][0], l1 = glds[t][1], l2 = glds[t][2];
        float m = fmaxf(l0, fmaxf(l1, l2));
        float e0 = expf(l0 - m), e1 = expf(l1 - m), e2 = expf(l2 - m);
        float inv = 1.f / (e0 + e1 + e2);
        glds[t][0] = e0 * inv; glds[t][1] = e1 * inv; glds[t][2] = e2 * inv;
    }
    __syncthreads();            // P ready for all waves

    // ---- resident Wm2 b-frags: 8 col-tiles x 4 k-slices = 128 VGPRs ----
    bf8v bfr[8][4];
    {
        const unsigned short* Wm2 = WT + 32768 + 128;
        #pragma unroll
        for (int nt = 0; nt < 8; ++nt)
            #pragma unroll
            for (int s = 0; s < 4; ++s)
                bfr[nt][s] = *(const bf8v*)&Wm2[(nt * 16 + lm) * 256 + s * 32 + lq * 8];
    }

    // ---- edge loop: 6 chunks x 4 cells, wave-private, NO barriers ----
    int j2 = lane * 2;
    for (int chv = 0; chv < 6; ++chv) {
        int row = chv * 4 + w;          // 0..23
        int n = n0 + row;
        bool act = n < NC;              // wave-uniform
        int ct = 3;
        if (act && lane < KN) ct = conn[(size_t)n * KN + lane];
        unsigned long long mlb = __ballot(ct == 0);
        unsigned long long mfb = __ballot(ct == 1);
        unsigned long long mdb = __ballot(ct == 2);
        float icl = 1.f / fmaxf((float)__builtin_popcountll(mlb), 1.f);
        float icf = 1.f / fmaxf((float)__builtin_popcountll(mfb), 1.f);
        float icd = 1.f / fmaxf((float)__builtin_popcountll(mdb), 1.f);
        float slx = 0.f, sly = 0.f, sdx = 0.f, sdy = 0.f;
        const float* basep = nbr + (size_t)(act ? n : 0) * KN * DD + j2;
        #pragma unroll
        for (int k = 0; k < KN; ++k) {
            float2 v = {0.f, 0.f};
            if (act) v = *(const float2*)&basep[(size_t)k * DD];
            if ((mlb >> k) & 1) { slx += v.x; sly += v.y; }
            if ((mdb >> k) & 1) { sdx += v.x; sdy += v.y; }
            *(unsigned*)&ALr(w, k)[j2] = pk2(v.x, v.y);
        }
        *(unsigned*)&AGLr(row)[j2] = pk2(slx * icl, sly * icl);
        *(unsigned*)&AGDr(row)[j2] = pk2(sdx * icd, sdy * icd);
        // rows 26..31 of the Al slice stay garbage: masked out via mfb below
        __builtin_amdgcn_s_setprio(1);
        #pragma unroll
        for (int nt = 0; nt < 8; ++nt) {
            float pv = uP[row * DD + nt * 16 + lm];
            float msum = 0.f;
            #pragma unroll
            for (int mt2 = 0; mt2 < 2; ++mt2) {
                f4v acc = {0.f, 0.f, 0.f, 0.f};
                #pragma unroll
                for (int s = 0; s < 4; ++s) {
                    bf8v a = *(const bf8v*)&ALr(w, mt2 * 16 + lm)[s * 32 + lq * 8];
                    acc = __builtin_amdgcn_mfma_f32_16x16x32_bf16(a, bfr[nt][s], acc, 0, 0, 0);
                }
                #pragma unroll
                for (int r = 0; r < 4; ++r) {
                    int rr = mt2 * 16 + lq * 4 + r;
                    if ((mfb >> rr) & 1) msum += fmaxf(pv + acc[r], 0.f);
                }
            }
            msum += __shfl_xor(msum, 16, 64);
            msum += __shfl_xor(msum, 32, 64);
            if (lane < 16) AGMr(row)[nt * 16 + lane] = f2bf(msum * icf);
        }
        __builtin_amdgcn_s_setprio(0);
    }
    __syncthreads();            // aggs complete, Al free

    // ---- expert pass helper: acc += X @ W[m][koff..koff+127] (b-frags from L2) ----
    auto mfmaPassG = [&](const unsigned short* Xbase, int m, int koff, f4v* acc) {
        const unsigned short* Wb = WT + m * 32768 + koff + lq * 8;
        #pragma unroll
        for (int nt = 0; nt < 4; ++nt) {
            int col0 = colh * 64 + nt * 16;
            #pragma unroll
            for (int s = 0; s < 4; ++s) {
                bf8v a = *(const bf8v*)&Xbase[(mt * 16 + lm) * LDSB + s * 32 + lq * 8];
                bf8v b = *(const bf8v*)&Wb[(col0 + lm) * 256 + s * 32];
                acc[nt] = __builtin_amdgcn_mfma_f32_16x16x32_bf16(a, b, acc[nt], 0, 0, 0);
            }
        }
    };

    f4v oacc[4], acc[4];
    for (int nt = 0; nt < 4; ++nt) oacc[nt] = (f4v){0.f, 0.f, 0.f, 0.f};

    // --- local expert ---
    for (int nt = 0; nt < 4; ++nt) acc[nt] = (f4v){0.f, 0.f, 0.f, 0.f};
    mfmaPassG(XCr(0), 0, 0, acc);
    mfmaPassG(AGLr(0), 0, 128, acc);
    for (int nt = 0; nt < 4; ++nt) {
        int col = colh * 64 + nt * 16 + lm;
        for (int r = 0; r < 4; ++r) {
            int row = mt * 16 + lq * 4 + r;
            oacc[nt][r] += glds[row][0] * tanhf(acc[nt][r] + bl[col]);
        }
    }

    // --- functional expert ---
    for (int nt = 0; nt < 4; ++nt) acc[nt] = (f4v){0.f, 0.f, 0.f, 0.f};
    mfmaPassG(XCr(0), 2, 0, acc);
    mfmaPassG(AGMr(0), 2, 128, acc);
    for (int nt = 0; nt < 4; ++nt) {
        int col = colh * 64 + nt * 16 + lm;
        for (int r = 0; r < 4; ++r) {
            int row = mt * 16 + lq * 4 + r;
            oacc[nt][r] += glds[row][1] * tanhf(acc[nt][r] + bu[col]);
        }
    }

    // --- distant expert (CNF) ---
    for (int nt = 0; nt < 4; ++nt) acc[nt] = (f4v){0.f, 0.f, 0.f, 0.f};
    mfmaPassG(AGDr(0), 3, 128, acc);
    f4v hd[4], sst[4];
    for (int nt = 0; nt < 4; ++nt) {
        int col = colh * 64 + nt * 16 + lm;
        for (int r = 0; r < 4; ++r) {
            int row = mt * 16 + lq * 4 + r;
            int n = n0 + row;
            hd[nt][r] = acc[nt][r] + bc[col];
            sst[nt][r] = (row < CB && n < NC) ? cur[(size_t)n * DD + col] : 0.f;
        }
    }
    // resident Wc1 b-frags for this wave's columns (16 frags = 64 VGPRs)
    bf8v cfr[4][4];
    #pragma unroll
    for (int nt = 0; nt < 4; ++nt)
        #pragma unroll
        for (int s = 0; s < 4; ++s)
            cfr[nt][s] = *(const bf8v*)&WT[3 * 32768 + (colh * 64 + nt * 16 + lm) * 256 + s * 32 + lq * 8];

    // Xs tile = Al slice 0 (32 rows available, writes up to row 31 are in-bounds)
    for (int step = 0; step < 3; ++step) {
        for (int nt = 0; nt < 4; ++nt) {
            int col = colh * 64 + nt * 16 + lm;
            for (int r = 0; r < 4; ++r) {
                int row = mt * 16 + lq * 4 + r;
                ALr(0, row)[col] = f2bf(sst[nt][r]);
            }
        }
        __syncthreads();
        for (int nt = 0; nt < 4; ++nt) acc[nt] = (f4v){0.f, 0.f, 0.f, 0.f};
        #pragma unroll
        for (int nt = 0; nt < 4; ++nt) {
            #pragma unroll
            for (int s = 0; s < 4; ++s) {
                bf8v a = *(const bf8v*)&ALr(0, mt * 16 + lm)[s * 32 + lq * 8];
                acc[nt] = __builtin_amdgcn_mfma_f32_16x16x32_bf16(a, cfr[nt][s], acc[nt], 0, 0, 0);
            }
        }
        for (int nt = 0; nt < 4; ++nt)
            for (int r = 0; r < 4; ++r)
                sst[nt][r] += DTC * tanhf(acc[nt][r] + hd[nt][r]);
        __syncthreads();
    }

    // --- combine + store ---
    for (int nt = 0; nt < 4; ++nt) {
        int col = colh * 64 + nt * 16 + lm;
        for (int r = 0; r < 4; ++r) {
            int row = mt * 16 + lq * 4 + r;
            int n = n0 + row;
            if (row < CB && n < NC)
                out[(size_t)n * DD + col] = oacc[nt][r] + glds[row][2] * sst[nt][r];
        }
    }
}

extern "C" void kernel_launch(void* const* d_in, const int* in_sizes, int n_in,
                              void* d_out, int out_size, void* d_ws, size_t ws_size,
                              hipStream_t stream) {
    const float* cur     = (const float*)d_in[0];
    const float* nbr     = (const float*)d_in[1];
    const int*   conn    = (const int*)d_in[2];
    const float* W_local = (const float*)d_in[3];
    const float* b_local = (const float*)d_in[4];
    const float* W_msg   = (const float*)d_in[5];
    const float* b_msg   = (const float*)d_in[6];
    const float* W_upd   = (const float*)d_in[7];
    const float* b_upd   = (const float*)d_in[8];
    const float* W_cnf   = (const float*)d_in[9];
    const float* b_cnf   = (const float*)d_in[10];
    const float* Wg1     = (const float*)d_in[11];
    const float* bg1     = (const float*)d_in[12];
    const float* Wg2     = (const float*)d_in[13];
    const float* bg2     = (const float*)d_in[14];
    float* out = (float*)d_out;

    char* ws = (char*)d_ws;
    unsigned short* WT  = (unsigned short*)ws;              // 262144 B
    unsigned short* WgT = (unsigned short*)(ws + 262144);   // 16384 B

    hipLaunchKernelGGL(k_prep, dim3(544), dim3(256), 0, stream,
                       W_local, W_msg, W_upd, W_cnf, Wg1, WT, WgT);
    hipLaunchKernelGGL(kMega, dim3((NC + CB - 1) / CB), dim3(256), 0, stream,
                       cur, nbr, conn, WT, WgT, b_msg, b_local, b_upd, b_cnf,
                       bg1, Wg2, bg2, out);
}

// Round 5
// 472.246 us; speedup vs baseline: 1.2671x; 1.2671x over previous
//
#include <hip/hip_runtime.h>
#include <math.h>

#define NC 19683
#define KN 26
#define DD 128
#define HGN 64
#define LDSB 136
#define DTC 0.1f
#define CPW 8          // kE: cells per wave
#define CPB 32         // kE: cells per block (4 waves x 8)

using bf8v = __attribute__((ext_vector_type(8))) short;
using f4v  = __attribute__((ext_vector_type(4))) float;

static __device__ __forceinline__ unsigned short f2bf(float x) {
    union { float f; unsigned u; } v; v.f = x;
    unsigned r = v.u + 0x7fffu + ((v.u >> 16) & 1u);
    return (unsigned short)(r >> 16);
}
static __device__ __forceinline__ unsigned pk2(float a, float b) {
    return ((unsigned)f2bf(a)) | (((unsigned)f2bf(b)) << 16);
}

// ---------------- prep: transpose 4x [256,128] f32 weights -> [128][256] bf16; Wg1 -> [64][128] bf16 ----
__global__ __launch_bounds__(256) void k_prep(const float* __restrict__ Wl,
    const float* __restrict__ Wm, const float* __restrict__ Wu,
    const float* __restrict__ Wc, const float* __restrict__ Wg1,
    unsigned short* __restrict__ WT, unsigned short* __restrict__ WgT)
{
    int idx = blockIdx.x * 256 + threadIdx.x;   // 544*256 = 139264 exact
    if (idx < 131072) {
        int m = idx >> 15;
        int r = idx & 32767;
        int j = r >> 8;     // 0..127 output col
        int i = r & 255;    // 0..255 k
        const float* src = (m == 0) ? Wl : (m == 1) ? Wm : (m == 2) ? Wu : Wc;
        WT[idx] = f2bf(src[i * DD + j]);
    } else {
        int idx2 = idx - 131072;        // 0..8191
        int col = idx2 >> 7;            // 0..63
        int k = idx2 & 127;             // 0..127
        WgT[idx2] = f2bf(Wg1[k * HGN + col]);
    }
}

// ---------------- kE: P + edge pass. 32 cells/block, wave-private pipelined cell loop ----------------
__global__ __launch_bounds__(256, 2) void kE(const float* __restrict__ cur,
    const float* __restrict__ nbr, const int* __restrict__ conn,
    const unsigned short* __restrict__ WT, const float* __restrict__ b_msg,
    unsigned short* __restrict__ agg_l, unsigned short* __restrict__ agg_m,
    unsigned short* __restrict__ agg_d)
{
    __shared__ __align__(16) unsigned short Wt[128 * LDSB];   // 34,816 B (Wm1 then Wm2)
    __shared__ __align__(16) unsigned short Anb[110 * LDSB];  // 29,920 B (cur tile, then 4x26 nbr slices + 6 pad)
    __shared__ float Pbuf[CPB * DD];                          // 16,384 B
    int t = threadIdx.x;
    int n0 = blockIdx.x * CPB;
    int w = t >> 6, lane = t & 63;
    int lm = lane & 15, lq = lane >> 4;
    int j2 = lane * 2;

    // ---- stage cur rows 0..31 -> Anb rows 0..31 (bf16) ----
    for (int p = 0; p < 8; ++p) {
        int idx = p * 256 + t;              // 2048 = 32 rows * 64 float2
        int r = idx >> 6, c2 = (idx & 63) * 2;
        float2 v = {0.f, 0.f};
        if (n0 + r < NC) v = *(const float2*)&cur[(size_t)(n0 + r) * DD + c2];
        *(unsigned*)&Anb[r * LDSB + c2] = pk2(v.x, v.y);
    }
    // ---- stage Wm1 -> Wt ----
    {
        const unsigned short* Wm1 = WT + 32768;
        for (int p = 0; p < 8; ++p) {
            int ch = p * 256 + t;
            int j = ch >> 4, i8 = (ch & 15) * 8;
            *(bf8v*)&Wt[j * LDSB + i8] = *(const bf8v*)&Wm1[j * 256 + i8];
        }
    }
    __syncthreads();

    // ---- prefetch cell 0 of this wave (conn + 26 nbr rows) — in flight across P-pass ----
    int cw0 = n0 + w * CPW;
    float2 vv[KN];
    int ct = 3;
    {
        bool a = cw0 < NC;
        if (a && lane < KN) ct = conn[(size_t)cw0 * KN + lane];
        const float* bp = nbr + (size_t)(a ? cw0 : 0) * KN * DD + j2;
        #pragma unroll
        for (int k = 0; k < KN; ++k) {
            float2 v = {0.f, 0.f};
            if (a) v = *(const float2*)&bp[(size_t)k * DD];
            vv[k] = v;
        }
    }

    // ---- P-pass: P[32][128] = cur @ Wm1 + b_msg ; wave w -> cols w*32..w*32+31 ----
    for (int nt = 0; nt < 2; ++nt) {
        int col0 = w * 32 + nt * 16;
        float bm = b_msg[col0 + lm];
        for (int mt2 = 0; mt2 < 2; ++mt2) {
            f4v acc = {0.f, 0.f, 0.f, 0.f};
            #pragma unroll
            for (int s = 0; s < 4; ++s) {
                bf8v a = *(const bf8v*)&Anb[(mt2 * 16 + lm) * LDSB + s * 32 + lq * 8];
                bf8v b = *(const bf8v*)&Wt[(col0 + lm) * LDSB + s * 32 + lq * 8];
                acc = __builtin_amdgcn_mfma_f32_16x16x32_bf16(a, b, acc, 0, 0, 0);
            }
            for (int r = 0; r < 4; ++r) {
                int row = mt2 * 16 + lq * 4 + r;
                Pbuf[row * DD + col0 + lm] = acc[r] + bm;
            }
        }
    }
    __syncthreads();            // P done; cur/Wm1 fully consumed

    // ---- restage Wt <- Wm2 ----
    {
        const unsigned short* Wm2 = WT + 32768 + 128;
        for (int p = 0; p < 8; ++p) {
            int ch = p * 256 + t;
            int j = ch >> 4, i8 = (ch & 15) * 8;
            *(bf8v*)&Wt[j * LDSB + i8] = *(const bf8v*)&Wm2[j * 256 + i8];
        }
    }
    __syncthreads();            // Wt=Wm2 ready; Anb free

    // ---- edge loop: CPW cells per wave, software-pipelined, no barriers ----
    int abase = w * KN;         // this wave's Anb slice base row
    for (int i = 0; i < CPW; ++i) {
        int n = cw0 + i;
        if (n >= NC) break;     // wave-uniform
        unsigned long long mlb = __ballot(ct == 0);
        unsigned long long mfb = __ballot(ct == 1);
        unsigned long long mdb = __ballot(ct == 2);
        float icl = 1.f / fmaxf((float)__builtin_popcountll(mlb), 1.f);
        float icf = 1.f / fmaxf((float)__builtin_popcountll(mfb), 1.f);
        float icd = 1.f / fmaxf((float)__builtin_popcountll(mdb), 1.f);
        float slx = 0.f, sly = 0.f, sdx = 0.f, sdy = 0.f;
        #pragma unroll
        for (int k = 0; k < KN; ++k) {
            float2 v = vv[k];
            if ((mlb >> k) & 1) { slx += v.x; sly += v.y; }
            if ((mdb >> k) & 1) { sdx += v.x; sdy += v.y; }
            *(unsigned*)&Anb[(abase + k) * LDSB + j2] = pk2(v.x, v.y);
        }
        *(unsigned*)&agg_l[(size_t)n * DD + j2] = pk2(slx * icl, sly * icl);
        *(unsigned*)&agg_d[(size_t)n * DD + j2] = pk2(sdx * icd, sdy * icd);

        // prefetch next cell: reuse vv regs right after their last read above,
        // so these 27 loads are in flight during the MFMA phase below
        if (i + 1 < CPW) {
            int n2 = cw0 + i + 1;
            bool a2 = n2 < NC;
            int ct2 = 3;
            if (a2 && lane < KN) ct2 = conn[(size_t)n2 * KN + lane];
            const float* bp2 = nbr + (size_t)(a2 ? n2 : 0) * KN * DD + j2;
            #pragma unroll
            for (int k = 0; k < KN; ++k) {
                float2 v = {0.f, 0.f};
                if (a2) v = *(const float2*)&bp2[(size_t)k * DD];
                vv[k] = v;
            }
            ct = ct2;
        }

        // A-fragments once (rows 26..31 of slice = neighbor slice garbage, masked via mfb)
        bf8v afr[2][4];
        #pragma unroll
        for (int mt2 = 0; mt2 < 2; ++mt2)
            #pragma unroll
            for (int s = 0; s < 4; ++s)
                afr[mt2][s] = *(const bf8v*)&Anb[(abase + mt2 * 16 + lm) * LDSB + s * 32 + lq * 8];

        int prow = (w * CPW + i) * DD;
        __builtin_amdgcn_s_setprio(1);
        #pragma unroll
        for (int nt = 0; nt < 8; ++nt) {
            float pv = Pbuf[prow + nt * 16 + lm];
            f4v a0 = {0.f, 0.f, 0.f, 0.f}, a1 = {0.f, 0.f, 0.f, 0.f};
            #pragma unroll
            for (int s = 0; s < 4; ++s) {
                bf8v b = *(const bf8v*)&Wt[(nt * 16 + lm) * LDSB + s * 32 + lq * 8];
                a0 = __builtin_amdgcn_mfma_f32_16x16x32_bf16(afr[0][s], b, a0, 0, 0, 0);
                a1 = __builtin_amdgcn_mfma_f32_16x16x32_bf16(afr[1][s], b, a1, 0, 0, 0);
            }
            float msum = 0.f;
            #pragma unroll
            for (int r = 0; r < 4; ++r) {
                int rr = lq * 4 + r;
                if ((mfb >> rr) & 1) msum += fmaxf(pv + a0[r], 0.f);
                int rr2 = 16 + lq * 4 + r;
                if ((mfb >> rr2) & 1) msum += fmaxf(pv + a1[r], 0.f);
            }
            msum += __shfl_xor(msum, 16, 64);
            msum += __shfl_xor(msum, 32, 64);
            if (lane < 16) agg_m[(size_t)n * DD + nt * 16 + lane] = f2bf(msum * icf);
        }
        __builtin_amdgcn_s_setprio(0);
    }
}

// ---------------- kC: gates + experts + gated combine. 32 cells/block (verified round-2 version) ----
__global__ __launch_bounds__(256) void kC(const float* __restrict__ cur,
    const unsigned short* __restrict__ WT, const unsigned short* __restrict__ WgT,
    const unsigned short* __restrict__ agg_l, const unsigned short* __restrict__ agg_m,
    const unsigned short* __restrict__ agg_d,
    const float* __restrict__ b_local, const float* __restrict__ b_upd,
    const float* __restrict__ b_cnf, const float* __restrict__ bg1,
    const float* __restrict__ Wg2, const float* __restrict__ bg2,
    float* __restrict__ out)
{
    __shared__ __align__(16) unsigned short Wl[128][LDSB];
    __shared__ __align__(16) unsigned short Xc[32][LDSB];
    __shared__ __align__(16) unsigned short Xa[32][LDSB];
    __shared__ float hrelu[32][HGN + 4];
    __shared__ float glds[32][4];
    __shared__ float bl[DD], bu[DD], bc[DD];
    __shared__ float Wg2s[HGN * 3];
    __shared__ float bg2s[4];
    int t = threadIdx.x;
    int n0 = blockIdx.x * 32;
    int w = t >> 6, lane = t & 63;
    int mt = w & 1, colh = w >> 1;
    int lm = lane & 15, lq = lane >> 4;

    auto stageW = [&](int m, int koff) {
        const unsigned short* src = WT + m * 32768 + koff;
        for (int p = 0; p < 8; ++p) {
            int ch = p * 256 + t;
            int j = ch >> 4, i8 = (ch & 15) * 8;
            *(bf8v*)&Wl[j][i8] = *(const bf8v*)&src[j * 256 + i8];
        }
    };
    auto stageXa = [&](const unsigned short* src) {
        for (int p = 0; p < 2; ++p) {
            int idx = p * 256 + t;
            int r = idx >> 4, c8 = (idx & 15) * 8;
            bf8v v = {0, 0, 0, 0, 0, 0, 0, 0};
            if (n0 + r < NC) v = *(const bf8v*)&src[(size_t)(n0 + r) * DD + c8];
            *(bf8v*)&Xa[r][c8] = v;
        }
    };
    auto mfmaPass = [&](unsigned short (&X)[32][LDSB], f4v* acc) {
        for (int nt = 0; nt < 4; ++nt) {
            int col0 = colh * 64 + nt * 16;
            for (int s = 0; s < 4; ++s) {
                bf8v a = *(const bf8v*)&X[mt * 16 + lm][s * 32 + lq * 8];
                bf8v b = *(const bf8v*)&Wl[col0 + lm][s * 32 + lq * 8];
                acc[nt] = __builtin_amdgcn_mfma_f32_16x16x32_bf16(a, b, acc[nt], 0, 0, 0);
            }
        }
    };

    // ---- stage Xc, WgT -> Wl rows 0..63, biases, gating head weights ----
    for (int p = 0; p < 8; ++p) {
        int idx = p * 256 + t;
        int r = idx >> 6, c2 = (idx & 63) * 2;
        float2 v = {0.f, 0.f};
        if (n0 + r < NC) v = *(const float2*)&cur[(size_t)(n0 + r) * DD + c2];
        *(unsigned*)&Xc[r][c2] = pk2(v.x, v.y);
    }
    for (int p = 0; p < 4; ++p) {
        int ch = p * 256 + t;
        int j = ch >> 4, i8 = (ch & 15) * 8;
        *(bf8v*)&Wl[j][i8] = *(const bf8v*)&WgT[j * 128 + i8];
    }
    if (t < 128) { bl[t] = b_local[t]; bu[t] = b_upd[t]; bc[t] = b_cnf[t]; }
    for (int i = t; i < HGN * 3; i += 256) Wg2s[i] = Wg2[i];   // all 192 entries
    if (t < 3) bg2s[t] = bg2[t];
    __syncthreads();

    // ---- gates MFMA: wave w -> cols w*16..w*16+15 of 64 ----
    {
        int col0 = w * 16;
        float bg = bg1[col0 + lm];
        for (int mt2 = 0; mt2 < 2; ++mt2) {
            f4v acc = {0.f, 0.f, 0.f, 0.f};
            for (int s = 0; s < 4; ++s) {
                bf8v a = *(const bf8v*)&Xc[mt2 * 16 + lm][s * 32 + lq * 8];
                bf8v b = *(const bf8v*)&Wl[col0 + lm][s * 32 + lq * 8];
                acc = __builtin_amdgcn_mfma_f32_16x16x32_bf16(a, b, acc, 0, 0, 0);
            }
            for (int r = 0; r < 4; ++r)
                hrelu[mt2 * 16 + lq * 4 + r][col0 + lm] = fmaxf(acc[r] + bg, 0.f);
        }
    }
    __syncthreads();

    // ---- stage W_local k0 while 96 threads compute gate logits ----
    stageW(0, 0);
    if (t < 96) {
        int r = t / 3, e = t - r * 3;
        float s = bg2s[e];
        for (int g = 0; g < HGN; ++g) s += hrelu[r][g] * Wg2s[g * 3 + e];
        glds[r][e] = s;
    }
    __syncthreads();

    // ---- softmax (32 threads) overlapped with local-expert cur-half MFMA ----
    if (t < 32) {
        float l0 = glds[t][0], l1 = glds[t][1], l2 = glds[t][2];
        float m = fmaxf(l0, fmaxf(l1, l2));
        float e0 = expf(l0 - m), e1 = expf(l1 - m), e2 = expf(l2 - m);
        float inv = 1.f / (e0 + e1 + e2);
        glds[t][0] = e0 * inv; glds[t][1] = e1 * inv; glds[t][2] = e2 * inv;
    }
    f4v oacc[4], acc[4];
    for (int nt = 0; nt < 4; ++nt) oacc[nt] = (f4v){0.f, 0.f, 0.f, 0.f};

    // --- local expert ---
    for (int nt = 0; nt < 4; ++nt) acc[nt] = (f4v){0.f, 0.f, 0.f, 0.f};
    mfmaPass(Xc, acc);
    __syncthreads();
    stageW(0, 128); stageXa(agg_l);
    __syncthreads();
    mfmaPass(Xa, acc);
    for (int nt = 0; nt < 4; ++nt) {
        int col = colh * 64 + nt * 16 + lm;
        for (int r = 0; r < 4; ++r) {
            int row = mt * 16 + lq * 4 + r;
            oacc[nt][r] += glds[row][0] * tanhf(acc[nt][r] + bl[col]);
        }
    }

    // --- functional expert ---
    __syncthreads();
    stageW(2, 0);
    __syncthreads();
    for (int nt = 0; nt < 4; ++nt) acc[nt] = (f4v){0.f, 0.f, 0.f, 0.f};
    mfmaPass(Xc, acc);
    __syncthreads();
    stageW(2, 128); stageXa(agg_m);
    __syncthreads();
    mfmaPass(Xa, acc);
    for (int nt = 0; nt < 4; ++nt) {
        int col = colh * 64 + nt * 16 + lm;
        for (int r = 0; r < 4; ++r) {
            int row = mt * 16 + lq * 4 + r;
            oacc[nt][r] += glds[row][1] * tanhf(acc[nt][r] + bu[col]);
        }
    }

    // --- distant expert (CNF) ---
    __syncthreads();
    stageW(3, 128); stageXa(agg_d);
    __syncthreads();
    for (int nt = 0; nt < 4; ++nt) acc[nt] = (f4v){0.f, 0.f, 0.f, 0.f};
    mfmaPass(Xa, acc);
    f4v hd[4], s[4];
    for (int nt = 0; nt < 4; ++nt) {
        int col = colh * 64 + nt * 16 + lm;
        for (int r = 0; r < 4; ++r) {
            int row = mt * 16 + lq * 4 + r;
            int n = n0 + row;
            hd[nt][r] = acc[nt][r] + bc[col];
            s[nt][r] = (n < NC) ? cur[(size_t)n * DD + col] : 0.f;
        }
    }
    __syncthreads();
    stageW(3, 0);   // Wc1, persists across steps
    for (int step = 0; step < 3; ++step) {
        for (int nt = 0; nt < 4; ++nt) {
            int col = colh * 64 + nt * 16 + lm;
            for (int r = 0; r < 4; ++r) {
                int row = mt * 16 + lq * 4 + r;
                Xa[row][col] = f2bf(s[nt][r]);
            }
        }
        __syncthreads();
        for (int nt = 0; nt < 4; ++nt) acc[nt] = (f4v){0.f, 0.f, 0.f, 0.f};
        mfmaPass(Xa, acc);
        for (int nt = 0; nt < 4; ++nt)
            for (int r = 0; r < 4; ++r)
                s[nt][r] += DTC * tanhf(acc[nt][r] + hd[nt][r]);
        __syncthreads();
    }

    // --- combine + store ---
    for (int nt = 0; nt < 4; ++nt) {
        int col = colh * 64 + nt * 16 + lm;
        for (int r = 0; r < 4; ++r) {
            int row = mt * 16 + lq * 4 + r;
            int n = n0 + row;
            if (n < NC) out[(size_t)n * DD + col] = oacc[nt][r] + glds[row][2] * s[nt][r];
        }
    }
}

extern "C" void kernel_launch(void* const* d_in, const int* in_sizes, int n_in,
                              void* d_out, int out_size, void* d_ws, size_t ws_size,
                              hipStream_t stream) {
    const float* cur     = (const float*)d_in[0];
    const float* nbr     = (const float*)d_in[1];
    const int*   conn    = (const int*)d_in[2];
    const float* W_local = (const float*)d_in[3];
    const float* b_local = (const float*)d_in[4];
    const float* W_msg   = (const float*)d_in[5];
    const float* b_msg   = (const float*)d_in[6];
    const float* W_upd   = (const float*)d_in[7];
    const float* b_upd   = (const float*)d_in[8];
    const float* W_cnf   = (const float*)d_in[9];
    const float* b_cnf   = (const float*)d_in[10];
    const float* Wg1     = (const float*)d_in[11];
    const float* bg1     = (const float*)d_in[12];
    const float* Wg2     = (const float*)d_in[13];
    const float* bg2     = (const float*)d_in[14];
    float* out = (float*)d_out;

    char* ws = (char*)d_ws;
    unsigned short* WT   = (unsigned short*)ws;                      // 262144 B
    unsigned short* WgT  = (unsigned short*)(ws + 262144);           // 16384 B
    unsigned short* aggl = (unsigned short*)(ws + 278528);           // 5038848 B each
    unsigned short* aggm = aggl + (size_t)NC * DD;
    unsigned short* aggd = aggm + (size_t)NC * DD;

    hipLaunchKernelGGL(k_prep, dim3(544), dim3(256), 0, stream,
                       W_local, W_msg, W_upd, W_cnf, Wg1, WT, WgT);
    hipLaunchKernelGGL(kE, dim3((NC + CPB - 1) / CPB), dim3(256), 0, stream,
                       cur, nbr, conn, WT, b_msg, aggl, aggm, aggd);
    hipLaunchKernelGGL(kC, dim3(616), dim3(256), 0, stream, cur, WT, WgT, aggl, aggm, aggd,
                       b_local, b_upd, b_cnf, bg1, Wg2, bg2, out);
}

// Round 6
// 467.322 us; speedup vs baseline: 1.2805x; 1.0105x over previous
//
#include <hip/hip_runtime.h>
#include <math.h>

#define NC 19683
#define KN 26
#define DD 128
#define HGN 64
#define LDSB 136
#define DTC 0.1f
#define CPW 8          // kE: cells per wave
#define CPB 32         // kE: cells per block (4 waves x 8)

using bf8v = __attribute__((ext_vector_type(8))) short;
using f4v  = __attribute__((ext_vector_type(4))) float;

static __device__ __forceinline__ unsigned short f2bf(float x) {
    union { float f; unsigned u; } v; v.f = x;
    unsigned r = v.u + 0x7fffu + ((v.u >> 16) & 1u);
    return (unsigned short)(r >> 16);
}
static __device__ __forceinline__ unsigned pk2(float a, float b) {
    return ((unsigned)f2bf(a)) | (((unsigned)f2bf(b)) << 16);
}

// ---------------- prep: transpose 4x [256,128] f32 weights -> [128][256] bf16; Wg1 -> [64][128] bf16 ----
__global__ __launch_bounds__(256) void k_prep(const float* __restrict__ Wl,
    const float* __restrict__ Wm, const float* __restrict__ Wu,
    const float* __restrict__ Wc, const float* __restrict__ Wg1,
    unsigned short* __restrict__ WT, unsigned short* __restrict__ WgT)
{
    int idx = blockIdx.x * 256 + threadIdx.x;   // 544*256 = 139264 exact
    if (idx < 131072) {
        int m = idx >> 15;
        int r = idx & 32767;
        int j = r >> 8;     // 0..127 output col
        int i = r & 255;    // 0..255 k
        const float* src = (m == 0) ? Wl : (m == 1) ? Wm : (m == 2) ? Wu : Wc;
        WT[idx] = f2bf(src[i * DD + j]);
    } else {
        int idx2 = idx - 131072;        // 0..8191
        int col = idx2 >> 7;            // 0..63
        int k = idx2 & 127;             // 0..127
        WgT[idx2] = f2bf(Wg1[k * HGN + col]);
    }
}

// ---------------- kE: P + edge pass. 32 cells/block, depth-2 prefetched wave-private cell loop ----------------
__global__ __launch_bounds__(256, 2) void kE(const float* __restrict__ cur,
    const float* __restrict__ nbr, const int* __restrict__ conn,
    const unsigned short* __restrict__ WT, const float* __restrict__ b_msg,
    unsigned short* __restrict__ agg_l, unsigned short* __restrict__ agg_m,
    unsigned short* __restrict__ agg_d)
{
    __shared__ __align__(16) unsigned short Wt[128 * LDSB];   // 34,816 B (Wm2, staged once)
    __shared__ __align__(16) unsigned short Anb[110 * LDSB];  // 29,920 B (cur tile, then 4x26 nbr slices)
    __shared__ float Pbuf[CPB * DD];                          // 16,384 B
    int t = threadIdx.x;
    int n0 = blockIdx.x * CPB;
    int w = t >> 6, lane = t & 63;
    int lm = lane & 15, lq = lane >> 4;
    int j2 = lane * 2;
    int cw0 = n0 + w * CPW;

    // ---- stage cur rows 0..31 -> Anb rows 0..31 (bf16) ----
    for (int p = 0; p < 8; ++p) {
        int idx = p * 256 + t;              // 2048 = 32 rows * 64 float2
        int r = idx >> 6, c2 = (idx & 63) * 2;
        float2 v = {0.f, 0.f};
        if (n0 + r < NC) v = *(const float2*)&cur[(size_t)(n0 + r) * DD + c2];
        *(unsigned*)&Anb[r * LDSB + c2] = pk2(v.x, v.y);
    }
    // ---- stage Wm2 -> Wt (once; P-pass reads its B straight from L2) ----
    {
        const unsigned short* Wm2 = WT + 32768 + 128;
        for (int p = 0; p < 8; ++p) {
            int ch = p * 256 + t;
            int j = ch >> 4, i8 = (ch & 15) * 8;
            *(bf8v*)&Wt[j * LDSB + i8] = *(const bf8v*)&Wm2[j * 256 + i8];
        }
    }

    // ---- depth-2 prefetch: cells 0 (A) and 1 (B) of this wave ----
    float2 vvA[KN], vvB[KN];
    int ctA = 3, ctB = 3;
    {
        int n1 = cw0;
        bool a = n1 < NC;
        if (a && lane < KN) ctA = conn[(size_t)n1 * KN + lane];
        const float* bp = nbr + (size_t)(a ? n1 : 0) * KN * DD + j2;
        #pragma unroll
        for (int k = 0; k < KN; ++k) {
            float2 v = {0.f, 0.f};
            if (a) v = *(const float2*)&bp[(size_t)k * DD];
            vvA[k] = v;
        }
    }
    {
        int n1 = cw0 + 1;
        bool a = n1 < NC;
        if (a && lane < KN) ctB = conn[(size_t)n1 * KN + lane];
        const float* bp = nbr + (size_t)(a ? n1 : 0) * KN * DD + j2;
        #pragma unroll
        for (int k = 0; k < KN; ++k) {
            float2 v = {0.f, 0.f};
            if (a) v = *(const float2*)&bp[(size_t)k * DD];
            vvB[k] = v;
        }
    }
    __syncthreads();

    // ---- P-pass: P[32][128] = cur @ Wm1 + b_msg ; wave w -> cols w*32..w*32+31; B from L2 ----
    {
        const unsigned short* Wm1 = WT + 32768;
        for (int nt = 0; nt < 2; ++nt) {
            int col0 = w * 32 + nt * 16;
            float bm = b_msg[col0 + lm];
            const unsigned short* bb = &Wm1[(col0 + lm) * 256 + lq * 8];
            for (int mt2 = 0; mt2 < 2; ++mt2) {
                f4v acc = {0.f, 0.f, 0.f, 0.f};
                #pragma unroll
                for (int s = 0; s < 4; ++s) {
                    bf8v a = *(const bf8v*)&Anb[(mt2 * 16 + lm) * LDSB + s * 32 + lq * 8];
                    bf8v b = *(const bf8v*)&bb[s * 32];
                    acc = __builtin_amdgcn_mfma_f32_16x16x32_bf16(a, b, acc, 0, 0, 0);
                }
                for (int r = 0; r < 4; ++r) {
                    int row = mt2 * 16 + lq * 4 + r;
                    Pbuf[row * DD + col0 + lm] = acc[r] + bm;
                }
            }
        }
    }
    __syncthreads();            // P ready for all waves; Anb cur region free

    // ---- edge loop: wave-private, no barriers, depth-2 software pipeline ----
    int abase = w * KN;         // this wave's Anb slice base row
    auto edge_cell = [&](float2 (&vv)[KN], int &ctR, int i) {
        int n = cw0 + i;
        if (n >= NC) return;    // wave-uniform
        unsigned long long mlb = __ballot(ctR == 0);
        unsigned long long mfb = __ballot(ctR == 1);
        unsigned long long mdb = __ballot(ctR == 2);
        float icl = 1.f / fmaxf((float)__builtin_popcountll(mlb), 1.f);
        float icf = 1.f / fmaxf((float)__builtin_popcountll(mfb), 1.f);
        float icd = 1.f / fmaxf((float)__builtin_popcountll(mdb), 1.f);
        float slx = 0.f, sly = 0.f, sdx = 0.f, sdy = 0.f;
        #pragma unroll
        for (int k = 0; k < KN; ++k) {
            float2 v = vv[k];
            if ((mlb >> k) & 1) { slx += v.x; sly += v.y; }
            if ((mdb >> k) & 1) { sdx += v.x; sdy += v.y; }
            *(unsigned*)&Anb[(abase + k) * LDSB + j2] = pk2(v.x, v.y);
        }
        *(unsigned*)&agg_l[(size_t)n * DD + j2] = pk2(slx * icl, sly * icl);
        *(unsigned*)&agg_d[(size_t)n * DD + j2] = pk2(sdx * icd, sdy * icd);

        // refill this buffer with cell i+2 (in flight across this cell's MFMA
        // phase AND the next cell's whole iteration)
        {
            int n2 = cw0 + i + 2;
            bool a2 = (i + 2 < CPW) && (n2 < NC);
            int ctn = 3;
            if (a2 && lane < KN) ctn = conn[(size_t)n2 * KN + lane];
            const float* bp2 = nbr + (size_t)(a2 ? n2 : 0) * KN * DD + j2;
            #pragma unroll
            for (int k = 0; k < KN; ++k) {
                float2 v = {0.f, 0.f};
                if (a2) v = *(const float2*)&bp2[(size_t)k * DD];
                vv[k] = v;
            }
            ctR = ctn;
        }
        // pin the refill loads before the MFMA phase — scheduler may not sink them
        __builtin_amdgcn_sched_barrier(0);

        // A-fragments (rows 26..31 of slice are neighbor-slice garbage, masked via mfb)
        bf8v afr[2][4];
        #pragma unroll
        for (int mt2 = 0; mt2 < 2; ++mt2)
            #pragma unroll
            for (int s = 0; s < 4; ++s)
                afr[mt2][s] = *(const bf8v*)&Anb[(abase + mt2 * 16 + lm) * LDSB + s * 32 + lq * 8];

        int prow = (w * CPW + i) * DD;
        #pragma unroll
        for (int nt = 0; nt < 8; ++nt) {
            float pv = Pbuf[prow + nt * 16 + lm];
            f4v a0 = {0.f, 0.f, 0.f, 0.f}, a1 = {0.f, 0.f, 0.f, 0.f};
            #pragma unroll
            for (int s = 0; s < 4; ++s) {
                bf8v b = *(const bf8v*)&Wt[(nt * 16 + lm) * LDSB + s * 32 + lq * 8];
                a0 = __builtin_amdgcn_mfma_f32_16x16x32_bf16(afr[0][s], b, a0, 0, 0, 0);
                a1 = __builtin_amdgcn_mfma_f32_16x16x32_bf16(afr[1][s], b, a1, 0, 0, 0);
            }
            float msum = 0.f;
            #pragma unroll
            for (int r = 0; r < 4; ++r) {
                int rr = lq * 4 + r;
                if ((mfb >> rr) & 1) msum += fmaxf(pv + a0[r], 0.f);
                int rr2 = 16 + lq * 4 + r;
                if ((mfb >> rr2) & 1) msum += fmaxf(pv + a1[r], 0.f);
            }
            msum += __shfl_xor(msum, 16, 64);
            msum += __shfl_xor(msum, 32, 64);
            if (lane < 16) agg_m[(size_t)n * DD + nt * 16 + lane] = f2bf(msum * icf);
        }
    };

    for (int ii = 0; ii < CPW; ii += 2) {
        edge_cell(vvA, ctA, ii);
        edge_cell(vvB, ctB, ii + 1);
    }
}

// ---------------- kC: gates + experts + gated combine. 32 cells/block (verified round-2 version) ----
__global__ __launch_bounds__(256) void kC(const float* __restrict__ cur,
    const unsigned short* __restrict__ WT, const unsigned short* __restrict__ WgT,
    const unsigned short* __restrict__ agg_l, const unsigned short* __restrict__ agg_m,
    const unsigned short* __restrict__ agg_d,
    const float* __restrict__ b_local, const float* __restrict__ b_upd,
    const float* __restrict__ b_cnf, const float* __restrict__ bg1,
    const float* __restrict__ Wg2, const float* __restrict__ bg2,
    float* __restrict__ out)
{
    __shared__ __align__(16) unsigned short Wl[128][LDSB];
    __shared__ __align__(16) unsigned short Xc[32][LDSB];
    __shared__ __align__(16) unsigned short Xa[32][LDSB];
    __shared__ float hrelu[32][HGN + 4];
    __shared__ float glds[32][4];
    __shared__ float bl[DD], bu[DD], bc[DD];
    __shared__ float Wg2s[HGN * 3];
    __shared__ float bg2s[4];
    int t = threadIdx.x;
    int n0 = blockIdx.x * 32;
    int w = t >> 6, lane = t & 63;
    int mt = w & 1, colh = w >> 1;
    int lm = lane & 15, lq = lane >> 4;

    auto stageW = [&](int m, int koff) {
        const unsigned short* src = WT + m * 32768 + koff;
        for (int p = 0; p < 8; ++p) {
            int ch = p * 256 + t;
            int j = ch >> 4, i8 = (ch & 15) * 8;
            *(bf8v*)&Wl[j][i8] = *(const bf8v*)&src[j * 256 + i8];
        }
    };
    auto stageXa = [&](const unsigned short* src) {
        for (int p = 0; p < 2; ++p) {
            int idx = p * 256 + t;
            int r = idx >> 4, c8 = (idx & 15) * 8;
            bf8v v = {0, 0, 0, 0, 0, 0, 0, 0};
            if (n0 + r < NC) v = *(const bf8v*)&src[(size_t)(n0 + r) * DD + c8];
            *(bf8v*)&Xa[r][c8] = v;
        }
    };
    auto mfmaPass = [&](unsigned short (&X)[32][LDSB], f4v* acc) {
        for (int nt = 0; nt < 4; ++nt) {
            int col0 = colh * 64 + nt * 16;
            for (int s = 0; s < 4; ++s) {
                bf8v a = *(const bf8v*)&X[mt * 16 + lm][s * 32 + lq * 8];
                bf8v b = *(const bf8v*)&Wl[col0 + lm][s * 32 + lq * 8];
                acc[nt] = __builtin_amdgcn_mfma_f32_16x16x32_bf16(a, b, acc[nt], 0, 0, 0);
            }
        }
    };

    // ---- stage Xc, WgT -> Wl rows 0..63, biases, gating head weights ----
    for (int p = 0; p < 8; ++p) {
        int idx = p * 256 + t;
        int r = idx >> 6, c2 = (idx & 63) * 2;
        float2 v = {0.f, 0.f};
        if (n0 + r < NC) v = *(const float2*)&cur[(size_t)(n0 + r) * DD + c2];
        *(unsigned*)&Xc[r][c2] = pk2(v.x, v.y);
    }
    for (int p = 0; p < 4; ++p) {
        int ch = p * 256 + t;
        int j = ch >> 4, i8 = (ch & 15) * 8;
        *(bf8v*)&Wl[j][i8] = *(const bf8v*)&WgT[j * 128 + i8];
    }
    if (t < 128) { bl[t] = b_local[t]; bu[t] = b_upd[t]; bc[t] = b_cnf[t]; }
    for (int i = t; i < HGN * 3; i += 256) Wg2s[i] = Wg2[i];   // all 192 entries
    if (t < 3) bg2s[t] = bg2[t];
    __syncthreads();

    // ---- gates MFMA: wave w -> cols w*16..w*16+15 of 64 ----
    {
        int col0 = w * 16;
        float bg = bg1[col0 + lm];
        for (int mt2 = 0; mt2 < 2; ++mt2) {
            f4v acc = {0.f, 0.f, 0.f, 0.f};
            for (int s = 0; s < 4; ++s) {
                bf8v a = *(const bf8v*)&Xc[mt2 * 16 + lm][s * 32 + lq * 8];
                bf8v b = *(const bf8v*)&Wl[col0 + lm][s * 32 + lq * 8];
                acc = __builtin_amdgcn_mfma_f32_16x16x32_bf16(a, b, acc, 0, 0, 0);
            }
            for (int r = 0; r < 4; ++r)
                hrelu[mt2 * 16 + lq * 4 + r][col0 + lm] = fmaxf(acc[r] + bg, 0.f);
        }
    }
    __syncthreads();

    // ---- stage W_local k0 while 96 threads compute gate logits ----
    stageW(0, 0);
    if (t < 96) {
        int r = t / 3, e = t - r * 3;
        float s = bg2s[e];
        for (int g = 0; g < HGN; ++g) s += hrelu[r][g] * Wg2s[g * 3 + e];
        glds[r][e] = s;
    }
    __syncthreads();

    // ---- softmax (32 threads) overlapped with local-expert cur-half MFMA ----
    if (t < 32) {
        float l0 = glds[t][0], l1 = glds[t][1], l2 = glds[t][2];
        float m = fmaxf(l0, fmaxf(l1, l2));
        float e0 = expf(l0 - m), e1 = expf(l1 - m), e2 = expf(l2 - m);
        float inv = 1.f / (e0 + e1 + e2);
        glds[t][0] = e0 * inv; glds[t][1] = e1 * inv; glds[t][2] = e2 * inv;
    }
    f4v oacc[4], acc[4];
    for (int nt = 0; nt < 4; ++nt) oacc[nt] = (f4v){0.f, 0.f, 0.f, 0.f};

    // --- local expert ---
    for (int nt = 0; nt < 4; ++nt) acc[nt] = (f4v){0.f, 0.f, 0.f, 0.f};
    mfmaPass(Xc, acc);
    __syncthreads();
    stageW(0, 128); stageXa(agg_l);
    __syncthreads();
    mfmaPass(Xa, acc);
    for (int nt = 0; nt < 4; ++nt) {
        int col = colh * 64 + nt * 16 + lm;
        for (int r = 0; r < 4; ++r) {
            int row = mt * 16 + lq * 4 + r;
            oacc[nt][r] += glds[row][0] * tanhf(acc[nt][r] + bl[col]);
        }
    }

    // --- functional expert ---
    __syncthreads();
    stageW(2, 0);
    __syncthreads();
    for (int nt = 0; nt < 4; ++nt) acc[nt] = (f4v){0.f, 0.f, 0.f, 0.f};
    mfmaPass(Xc, acc);
    __syncthreads();
    stageW(2, 128); stageXa(agg_m);
    __syncthreads();
    mfmaPass(Xa, acc);
    for (int nt = 0; nt < 4; ++nt) {
        int col = colh * 64 + nt * 16 + lm;
        for (int r = 0; r < 4; ++r) {
            int row = mt * 16 + lq * 4 + r;
            oacc[nt][r] += glds[row][1] * tanhf(acc[nt][r] + bu[col]);
        }
    }

    // --- distant expert (CNF) ---
    __syncthreads();
    stageW(3, 128); stageXa(agg_d);
    __syncthreads();
    for (int nt = 0; nt < 4; ++nt) acc[nt] = (f4v){0.f, 0.f, 0.f, 0.f};
    mfmaPass(Xa, acc);
    f4v hd[4], s[4];
    for (int nt = 0; nt < 4; ++nt) {
        int col = colh * 64 + nt * 16 + lm;
        for (int r = 0; r < 4; ++r) {
            int row = mt * 16 + lq * 4 + r;
            int n = n0 + row;
            hd[nt][r] = acc[nt][r] + bc[col];
            s[nt][r] = (n < NC) ? cur[(size_t)n * DD + col] : 0.f;
        }
    }
    __syncthreads();
    stageW(3, 0);   // Wc1, persists across steps
    for (int step = 0; step < 3; ++step) {
        for (int nt = 0; nt < 4; ++nt) {
            int col = colh * 64 + nt * 16 + lm;
            for (int r = 0; r < 4; ++r) {
                int row = mt * 16 + lq * 4 + r;
                Xa[row][col] = f2bf(s[nt][r]);
            }
        }
        __syncthreads();
        for (int nt = 0; nt < 4; ++nt) acc[nt] = (f4v){0.f, 0.f, 0.f, 0.f};
        mfmaPass(Xa, acc);
        for (int nt = 0; nt < 4; ++nt)
            for (int r = 0; r < 4; ++r)
                s[nt][r] += DTC * tanhf(acc[nt][r] + hd[nt][r]);
        __syncthreads();
    }

    // --- combine + store ---
    for (int nt = 0; nt < 4; ++nt) {
        int col = colh * 64 + nt * 16 + lm;
        for (int r = 0; r < 4; ++r) {
            int row = mt * 16 + lq * 4 + r;
            int n = n0 + row;
            if (n < NC) out[(size_t)n * DD + col] = oacc[nt][r] + glds[row][2] * s[nt][r];
        }
    }
}

extern "C" void kernel_launch(void* const* d_in, const int* in_sizes, int n_in,
                              void* d_out, int out_size, void* d_ws, size_t ws_size,
                              hipStream_t stream) {
    const float* cur     = (const float*)d_in[0];
    const float* nbr     = (const float*)d_in[1];
    const int*   conn    = (const int*)d_in[2];
    const float* W_local = (const float*)d_in[3];
    const float* b_local = (const float*)d_in[4];
    const float* W_msg   = (const float*)d_in[5];
    const float* b_msg   = (const float*)d_in[6];
    const float* W_upd   = (const float*)d_in[7];
    const float* b_upd   = (const float*)d_in[8];
    const float* W_cnf   = (const float*)d_in[9];
    const float* b_cnf   = (const float*)d_in[10];
    const float* Wg1     = (const float*)d_in[11];
    const float* bg1     = (const float*)d_in[12];
    const float* Wg2     = (const float*)d_in[13];
    const float* bg2     = (const float*)d_in[14];
    float* out = (float*)d_out;

    char* ws = (char*)d_ws;
    unsigned short* WT   = (unsigned short*)ws;                      // 262144 B
    unsigned short* WgT  = (unsigned short*)(ws + 262144);           // 16384 B
    unsigned short* aggl = (unsigned short*)(ws + 278528);           // 5038848 B each
    unsigned short* aggm = aggl + (size_t)NC * DD;
    unsigned short* aggd = aggm + (size_t)NC * DD;

    hipLaunchKernelGGL(k_prep, dim3(544), dim3(256), 0, stream,
                       W_local, W_msg, W_upd, W_cnf, Wg1, WT, WgT);
    hipLaunchKernelGGL(kE, dim3((NC + CPB - 1) / CPB), dim3(256), 0, stream,
                       cur, nbr, conn, WT, b_msg, aggl, aggm, aggd);
    hipLaunchKernelGGL(kC, dim3(616), dim3(256), 0, stream, cur, WT, WgT, aggl, aggm, aggd,
                       b_local, b_upd, b_cnf, bg1, Wg2, bg2, out);
}